// Round 11
// baseline (290.259 us; speedup 1.0000x reference)
//
#include <hip/hip_runtime.h>
#include <hip/hip_bf16.h>
#include <math.h>

typedef __attribute__((ext_vector_type(8))) short short8;
typedef __attribute__((ext_vector_type(4))) float f32x4;

#define MFMA_BF16 __builtin_amdgcn_mfma_f32_16x16x32_bf16

static constexpr int Dm = 1024;
static constexpr int Tm = 2048;
static constexpr int Bb = 4;
static constexpr int NHm = 16;
static constexpr int HDm = 64;
static constexpr int Mtot = Bb * Tm;   // 8192
static constexpr int NKT = Tm / 64;    // 32 KV tiles per (b,h)
static constexpr float kQScale = 0.125f * 1.4426950408889634f;  // 1/sqrt(64) * log2(e)

__device__ __forceinline__ unsigned short f2bf(float f) {
  unsigned int u = __float_as_uint(f);
  u += 0x7FFFu + ((u >> 16) & 1u);  // RNE
  return (unsigned short)(u >> 16);
}

__device__ __forceinline__ float fexp2(float x) {  // raw v_exp_f32 (2^x)
  float r;
  asm("v_exp_f32 %0, %1" : "=v"(r) : "v"(x));
  return r;
}

__device__ __forceinline__ void gload16(const void* g, void* l) {
  __builtin_amdgcn_global_load_lds((const __attribute__((address_space(1))) void*)g,
                                   (__attribute__((address_space(3))) void*)l, 16, 0, 0);
}

__global__ __launch_bounds__(256) void cvt_kernel(const float* __restrict__ src,
                                                  short* __restrict__ dst, int n) {
  int stride = gridDim.x * blockDim.x;
  for (int i = blockIdx.x * blockDim.x + threadIdx.x; i * 4 < n; i += stride) {
    float4 v = reinterpret_cast<const float4*>(src)[i];
    short4 o;
    o.x = (short)f2bf(v.x);
    o.y = (short)f2bf(v.y);
    o.z = (short)f2bf(v.z);
    o.w = (short)f2bf(v.w);
    reinterpret_cast<short4*>(dst)[i] = o;
  }
}

// fused fp32->bf16 + transpose: Wt[n][k] = W[k][n], for all four weights
__global__ __launch_bounds__(256) void cvt_t_kernel(
    const float* __restrict__ W0, const float* __restrict__ W1,
    const float* __restrict__ W2, const float* __restrict__ W3,
    short* __restrict__ T0, short* __restrict__ T1,
    short* __restrict__ T2, short* __restrict__ T3) {
  const float* W = blockIdx.z == 0 ? W0 : blockIdx.z == 1 ? W1 : blockIdx.z == 2 ? W2 : W3;
  short* Wt = blockIdx.z == 0 ? T0 : blockIdx.z == 1 ? T1 : blockIdx.z == 2 ? T2 : T3;
  __shared__ __align__(16) short T[64 * 72];
  const int tid = threadIdx.x;
  const int k0 = blockIdx.y * 64, n0 = blockIdx.x * 64;
#pragma unroll
  for (int p = 0; p < 4; ++p) {
    int idx = tid + p * 256;
    int kr = idx >> 4, c4 = (idx & 15) * 4;
    float4 v = *reinterpret_cast<const float4*>(W + (size_t)(k0 + kr) * Dm + n0 + c4);
    T[(c4 + 0) * 72 + kr] = (short)f2bf(v.x);
    T[(c4 + 1) * 72 + kr] = (short)f2bf(v.y);
    T[(c4 + 2) * 72 + kr] = (short)f2bf(v.z);
    T[(c4 + 3) * 72 + kr] = (short)f2bf(v.w);
  }
  __syncthreads();
#pragma unroll
  for (int p = 0; p < 2; ++p) {
    int idx = tid + p * 256;
    int nr = idx >> 3, c8 = (idx & 7) * 8;
    *reinterpret_cast<short8*>(Wt + (size_t)(n0 + nr) * Dm + k0 + c8) =
        *reinterpret_cast<const short8*>(&T[nr * 72 + c8]);
  }
}

// ---- 128x128/BK=32 mainloop, A DIRECT-TO-REGISTER (halves LDS traffic) -----
// Theory (r10 post-mortem): kernel was LDS-pipe-bound (reads 1920 + writes 640
// vs MFMA 1536 cyc per CU-K-step). A-fragments load straight to VGPRs with a
// 1-step ping-pong prefetch (manual 2-step unroll -> compile-time indices,
// rule #20). Only B is LDS-staged (genuinely shared). Per step VMEM = 4 A +
// 2 B-gloads -> vmcnt(6) retires exactly the previous step's 6 (FIFO).
// B swizzle unchanged (verified 0 conflicts).
#define GSTEP(KT, CUR, PF)                                                    \
  {                                                                           \
    __builtin_amdgcn_s_barrier(); /* readers of Bs[CUR^1] done (prev iter) */ \
    if (PF) {                                                                 \
      _Pragma("unroll") for (int mi = 0; mi < 4; ++mi)                        \
          a[(CUR) ^ 1][mi] = *reinterpret_cast<const short8*>(                \
              Ar[mi] + ((KT) + 1) * 32);                                      \
      stageB((KT) + 1, (CUR) ^ 1);                                            \
      __builtin_amdgcn_sched_barrier(0);                                      \
      asm volatile("s_waitcnt vmcnt(6)" ::: "memory");                        \
    } else {                                                                  \
      asm volatile("s_waitcnt vmcnt(0)" ::: "memory");                        \
    }                                                                         \
    __builtin_amdgcn_s_barrier(); /* publish Bs[CUR] */                       \
    __builtin_amdgcn_sched_barrier(0);                                        \
    short8 b[4];                                                              \
    _Pragma("unroll") for (int ni = 0; ni < 4; ++ni)                          \
        b[ni] = *reinterpret_cast<const short8*>(                             \
            &Bs[(CUR) * 4096 + (wc + ni * 16 + lr) * 32 + csel]);             \
    _Pragma("unroll") for (int mi = 0; mi < 4; ++mi)                          \
        _Pragma("unroll") for (int ni = 0; ni < 4; ++ni)                      \
            acc[mi][ni] =                                                     \
                MFMA_BF16(a[CUR][mi], b[ni], acc[mi][ni], 0, 0, 0);           \
  }

__device__ __forceinline__ void gemm_mainloopA(
    const short* __restrict__ A, const short* __restrict__ B,
    int m0, int n0, short* Bs, f32x4 acc[4][4], int tid) {
  constexpr int NT = Dm / 32;  // 32
  const int lane = tid & 63;
  const int w = tid >> 6;
  const int wr = (w >> 1) * 64, wc = (w & 1) * 64;
  const int lr = lane & 15;
  const int g = lane >> 4;
  // B staging: 128x32 tile = 8KB = 512 chunks, 2/thread; swizzled global src
  const int rowt = tid >> 2;
  const int csw = ((tid & 3) ^ ((tid >> 3) & 3)) * 8;
  const short* Bsrc0 = B + (size_t)(n0 + rowt) * Dm + csw;
  const short* Bsrc1 = B + (size_t)(n0 + 64 + rowt) * Dm + csw;
  short* Bd0 = Bs + (w * 16) * 32;
  short* Bd1 = Bs + (64 + w * 16) * 32;
  auto stageB = [&](int kt, int buf) {
    gload16(Bsrc0 + kt * 32, Bd0 + buf * 4096);
    gload16(Bsrc1 + kt * 32, Bd1 + buf * 4096);
  };
  // A direct-to-reg fragment bases (per-lane)
  const short* Ar[4];
#pragma unroll
  for (int mi = 0; mi < 4; ++mi)
    Ar[mi] = A + (size_t)(m0 + wr + mi * 16 + lr) * Dm + g * 8;

  const int csel = (g ^ ((lr >> 1) & 3)) * 8;

  short8 a[2][4];
#pragma unroll
  for (int mi = 0; mi < 4; ++mi)
    a[0][mi] = *reinterpret_cast<const short8*>(Ar[mi]);
  stageB(0, 0);

  for (int kt2 = 0; kt2 < NT - 2; kt2 += 2) {
    GSTEP(kt2, 0, 1);
    GSTEP(kt2 + 1, 1, 1);
  }
  GSTEP(NT - 2, 0, 1);
  GSTEP(NT - 1, 1, 0);
}

// Fused QKV as ONE GEMM: A(8192x1024) @ WT3^T, WT3 = [Wq;Wk;Wv]^T [3072][1024].
// grid = (m=64, n=24): same-m blocks have id%8 == m%8 -> same XCD L2.
__global__ __launch_bounds__(256, 4) void gemm_qkv_kernel(
    const short* __restrict__ Ags, const short* __restrict__ WT3,
    short* __restrict__ Qo, short* __restrict__ Ko, short* __restrict__ Vo) {
  __shared__ __align__(16) short Bs[2 * 128 * 32];  // 16 KB
  const int tid = threadIdx.x;
  const int m0 = blockIdx.x * 128;
  const int n0g = blockIdx.y * 128;  // 0..3071
  const int z = n0g >> 10;
  const int n0 = n0g & 1023;
  short* Co = z == 0 ? Qo : z == 1 ? Ko : Vo;

  f32x4 acc[4][4];
#pragma unroll
  for (int mi = 0; mi < 4; ++mi)
#pragma unroll
    for (int ni = 0; ni < 4; ++ni)
#pragma unroll
      for (int r = 0; r < 4; ++r) acc[mi][ni][r] = 0.f;

  gemm_mainloopA(Ags, WT3, m0, n0g, Bs, acc, tid);

  const int lane = tid & 63;
  const int w = tid >> 6;
  const int wr = (w >> 1) * 64, wc = (w & 1) * 64;
  const int g = lane >> 4, lr = lane & 15;
#pragma unroll
  for (int mi = 0; mi < 4; ++mi)
#pragma unroll
    for (int ni = 0; ni < 4; ++ni)
#pragma unroll
      for (int r = 0; r < 4; ++r) {
        int mg = m0 + wr + mi * 16 + g * 4 + r;  // C/D: row=(lane>>4)*4+reg
        int ng = n0 + wc + ni * 16 + lr;         // C/D: col=lane&15
        float v = acc[mi][ni][r];
        int b_ = mg >> 11, t_ = mg & 2047, h_ = ng >> 6, d_ = ng & 63;
        size_t bh = (size_t)(b_ * NHm + h_);
        if (z == 0) {
          Co[(bh * Tm + t_) * HDm + d_] = (short)f2bf(v * kQScale);
        } else if (z == 1) {
          Co[((bh * NKT + (t_ >> 6)) << 12) + (t_ & 63) * 64 + (d_ ^ ((t_ & 7) << 3))] =
              (short)f2bf(v);
        } else {
          Co[((bh * NKT + (t_ >> 6)) << 12) + d_ * 64 + ((t_ & 63) ^ ((d_ & 7) << 3))] =
              (short)f2bf(v);
        }
      }
}

// Out-projection: fp32 + bias, row-major. grid = (m=64, n=8).
__global__ __launch_bounds__(256, 4) void gemm_out_kernel(
    const short* __restrict__ Ags, const short* __restrict__ Bts,
    float* __restrict__ Cf, const float* __restrict__ bias) {
  __shared__ __align__(16) short Bs[2 * 128 * 32];  // 16 KB
  const int tid = threadIdx.x;
  const int m0 = blockIdx.x * 128;
  const int n0 = blockIdx.y * 128;

  f32x4 acc[4][4];
#pragma unroll
  for (int mi = 0; mi < 4; ++mi)
#pragma unroll
    for (int ni = 0; ni < 4; ++ni)
#pragma unroll
      for (int r = 0; r < 4; ++r) acc[mi][ni][r] = 0.f;

  gemm_mainloopA(Ags, Bts, m0, n0, Bs, acc, tid);

  const int lane = tid & 63;
  const int w = tid >> 6;
  const int wr = (w >> 1) * 64, wc = (w & 1) * 64;
  const int g = lane >> 4, lr = lane & 15;
#pragma unroll
  for (int mi = 0; mi < 4; ++mi)
#pragma unroll
    for (int ni = 0; ni < 4; ++ni)
#pragma unroll
      for (int r = 0; r < 4; ++r) {
        int mg = m0 + wr + mi * 16 + g * 4 + r;
        int ng = n0 + wc + ni * 16 + lr;
        Cf[(size_t)mg * Dm + ng] = acc[mi][ni][r] + bias[ng];
      }
}

// Flash attention (unchanged): causal, fixed-offset softmax, l via ones-MFMA,
// 3-buffer 2-deep prefetch with counted vmcnt, XCD-local grid.
__global__ __launch_bounds__(256) void attn_kernel(
    const short* __restrict__ Qg, const short* __restrict__ Kg,
    const short* __restrict__ Vg, short* __restrict__ Og) {
  __shared__ __align__(16) short Kl[3][64 * 64];
  __shared__ __align__(16) short Vl[3][64 * 64];
  __shared__ __align__(16) short Pl[4][32 * 72];
  const int tid = threadIdx.x;
  const int lane = tid & 63;
  const int w = tid >> 6;
  const int g = lane >> 4;
  const int lr = lane & 15;
  const int bh = blockIdx.x;
  const int pi = blockIdx.y;
  const short* Ks = Kg + ((size_t)bh * NKT << 12);
  const short* Vs = Vg + ((size_t)bh * NKT << 12);
  short* Pw = &Pl[w][0];
  const int b_ = bh >> 4, h_ = bh & 15;

  short8 ones;
#pragma unroll
  for (int j = 0; j < 8; ++j) ones[j] = (short)0x3F80;  // bf16 1.0

  auto stage = [&](int t, int buf) {
#pragma unroll
    for (int i = 0; i < 2; ++i) {
      int ch = w * 2 + i;
      gload16(Ks + ((size_t)t << 12) + ch * 512 + lane * 8, &Kl[buf][ch * 512]);
      gload16(Vs + ((size_t)t << 12) + ch * 512 + lane * 8, &Vl[buf][ch * 512]);
    }
  };

  for (int pass = 0; pass < 2; ++pass) {
    const int qb = pass == 0 ? (15 - pi) : pi;
    const int q0 = qb * 128;
    const int qw = q0 + w * 32;
    const short* Qs = Qg + ((size_t)bh * Tm + q0) * HDm;

    short8 qf[2][2];
#pragma unroll
    for (int mi = 0; mi < 2; ++mi)
#pragma unroll
      for (int kk = 0; kk < 2; ++kk)
        qf[mi][kk] = *reinterpret_cast<const short8*>(
            Qs + (w * 32 + mi * 16 + lr) * HDm + kk * 32 + g * 8);

    f32x4 o[2][4], lacc[2];
#pragma unroll
    for (int mi = 0; mi < 2; ++mi)
#pragma unroll
      for (int r = 0; r < 4; ++r) {
        lacc[mi][r] = 0.f;
#pragma unroll
        for (int di = 0; di < 4; ++di) o[mi][di][r] = 0.f;
      }

    const int nt = q0 / 64 + 2;
    stage(0, 0);
    stage(1, 1);
    for (int t = 0; t < nt; ++t) {
      if (t < nt - 1) asm volatile("s_waitcnt vmcnt(4)" ::: "memory");
      else            asm volatile("s_waitcnt vmcnt(0)" ::: "memory");
      __builtin_amdgcn_s_barrier();
      __builtin_amdgcn_sched_barrier(0);
      if (t + 2 < nt) stage(t + 2, (t + 2) % 3);
      const int cur = t % 3;
      const int k0 = t * 64;
      const bool active = (k0 <= qw + 31);
      if (active) {
        short8 kf[2][4];
#pragma unroll
        for (int ni = 0; ni < 4; ++ni) {
          int row = ni * 16 + lr;
#pragma unroll
          for (int kk = 0; kk < 2; ++kk)
            kf[kk][ni] = *reinterpret_cast<const short8*>(
                &Kl[cur][row * 64 + ((kk * 32 + g * 8) ^ ((row & 7) << 3))]);
        }
        f32x4 s[2][4];
#pragma unroll
        for (int mi = 0; mi < 2; ++mi)
#pragma unroll
          for (int ni = 0; ni < 4; ++ni) {
            f32x4 acc;
#pragma unroll
            for (int r = 0; r < 4; ++r) acc[r] = 0.f;
            acc = MFMA_BF16(qf[mi][0], kf[0][ni], acc, 0, 0, 0);
            acc = MFMA_BF16(qf[mi][1], kf[1][ni], acc, 0, 0, 0);
            s[mi][ni] = acc;
          }
        if (k0 + 63 > qw) {
#pragma unroll
          for (int mi = 0; mi < 2; ++mi)
#pragma unroll
            for (int ni = 0; ni < 4; ++ni)
#pragma unroll
              for (int r = 0; r < 4; ++r)
                if (k0 + ni * 16 + lr > qw + mi * 16 + g * 4 + r) s[mi][ni][r] = -1e30f;
        }
#pragma unroll
        for (int mi = 0; mi < 2; ++mi)
#pragma unroll
          for (int ni = 0; ni < 4; ++ni)
#pragma unroll
            for (int r = 0; r < 4; ++r)
              Pw[(mi * 16 + g * 4 + r) * 72 + ((ni * 16 + lr) ^ (g << 4))] =
                  (short)f2bf(fexp2(s[mi][ni][r]));

#pragma unroll
        for (int kk = 0; kk < 2; ++kk) {
          short8 pf[2];
#pragma unroll
          for (int mi = 0; mi < 2; ++mi)
            pf[mi] = *reinterpret_cast<const short8*>(
                &Pw[(mi * 16 + lr) * 72 + ((kk * 32 + g * 8) ^ ((lr >> 2) << 4))]);
#pragma unroll
          for (int mi = 0; mi < 2; ++mi)
            lacc[mi] = MFMA_BF16(pf[mi], ones, lacc[mi], 0, 0, 0);
#pragma unroll
          for (int di = 0; di < 4; ++di) {
            int d = di * 16 + lr;
            short8 vf = *reinterpret_cast<const short8*>(
                &Vl[cur][d * 64 + ((kk * 32 + g * 8) ^ ((d & 7) << 3))]);
#pragma unroll
            for (int mi = 0; mi < 2; ++mi)
              o[mi][di] = MFMA_BF16(pf[mi], vf, o[mi][di], 0, 0, 0);
          }
        }
      }
    }
    __syncthreads();

#pragma unroll
    for (int mi = 0; mi < 2; ++mi)
#pragma unroll
      for (int di = 0; di < 4; ++di)
#pragma unroll
        for (int r = 0; r < 4; ++r) {
          float ov = o[mi][di][r] / lacc[mi][r];
          int qg = q0 + w * 32 + mi * 16 + g * 4 + r;
          int d_ = di * 16 + lr;
          Og[((size_t)b_ * Tm + qg) * Dm + h_ * HDm + d_] = (short)f2bf(ov);
        }
  }
}

extern "C" void kernel_launch(void* const* d_in, const int* in_sizes, int n_in,
                              void* d_out, int out_size, void* d_ws, size_t ws_size,
                              hipStream_t stream) {
  const float* X = (const float*)d_in[0];
  const float* Wq = (const float*)d_in[1];
  const float* Wk = (const float*)d_in[2];
  const float* Wv = (const float*)d_in[3];
  const float* Wo = (const float*)d_in[4];
  const float* bo = (const float*)d_in[5];
  float* out = (float*)d_out;

  char* ws = (char*)d_ws;
  short* Xb = (short*)ws;  ws += (size_t)Mtot * Dm * 2;
  short* Wqt = (short*)ws; ws += (size_t)Dm * Dm * 2;  // [3072][1024] contiguous
  short* Wkt = (short*)ws; ws += (size_t)Dm * Dm * 2;
  short* Wvt = (short*)ws; ws += (size_t)Dm * Dm * 2;
  short* Wot = (short*)ws; ws += (size_t)Dm * Dm * 2;
  short* Qb = (short*)ws;  ws += (size_t)Mtot * Dm * 2;
  short* Kb = (short*)ws;  ws += (size_t)Mtot * Dm * 2;
  short* Vb = (short*)ws;  ws += (size_t)Mtot * Dm * 2;
  short* Ab = (short*)ws;  ws += (size_t)Mtot * Dm * 2;

  cvt_kernel<<<dim3(1024), dim3(256), 0, stream>>>(X, Xb, Mtot * Dm);
  cvt_t_kernel<<<dim3(16, 16, 4), dim3(256), 0, stream>>>(Wq, Wk, Wv, Wo, Wqt, Wkt, Wvt, Wot);

  gemm_qkv_kernel<<<dim3(Mtot / 128, 3 * Dm / 128), 256, 0, stream>>>(
      Xb, Wqt, Qb, Kb, Vb);

  attn_kernel<<<dim3(Bb * NHm, 8), 256, 0, stream>>>(Qb, Kb, Vb, Ab);

  gemm_out_kernel<<<dim3(Mtot / 128, Dm / 128), 256, 0, stream>>>(Ab, Wot, out, bo);
}

// Round 12
// 228.582 us; speedup vs baseline: 1.2698x; 1.2698x over previous
//
#include <hip/hip_runtime.h>
#include <hip/hip_bf16.h>
#include <math.h>

typedef __attribute__((ext_vector_type(8))) short short8;
typedef __attribute__((ext_vector_type(4))) float f32x4;

#define MFMA_BF16 __builtin_amdgcn_mfma_f32_16x16x32_bf16

static constexpr int Dm = 1024;
static constexpr int Tm = 2048;
static constexpr int Bb = 4;
static constexpr int NHm = 16;
static constexpr int HDm = 64;
static constexpr int Mtot = Bb * Tm;   // 8192
static constexpr int NKT = Tm / 64;    // 32 KV tiles per (b,h)
static constexpr float kQScale = 0.125f * 1.4426950408889634f;  // 1/sqrt(64) * log2(e)

__device__ __forceinline__ unsigned short f2bf(float f) {
  unsigned int u = __float_as_uint(f);
  u += 0x7FFFu + ((u >> 16) & 1u);  // RNE
  return (unsigned short)(u >> 16);
}

__device__ __forceinline__ float fexp2(float x) {  // raw v_exp_f32 (2^x)
  float r;
  asm("v_exp_f32 %0, %1" : "=v"(r) : "v"(x));
  return r;
}

__device__ __forceinline__ void gload16(const void* g, void* l) {
  __builtin_amdgcn_global_load_lds((const __attribute__((address_space(1))) void*)g,
                                   (__attribute__((address_space(3))) void*)l, 16, 0, 0);
}

__global__ __launch_bounds__(256) void cvt_kernel(const float* __restrict__ src,
                                                  short* __restrict__ dst, int n) {
  int stride = gridDim.x * blockDim.x;
  for (int i = blockIdx.x * blockDim.x + threadIdx.x; i * 4 < n; i += stride) {
    float4 v = reinterpret_cast<const float4*>(src)[i];
    short4 o;
    o.x = (short)f2bf(v.x);
    o.y = (short)f2bf(v.y);
    o.z = (short)f2bf(v.z);
    o.w = (short)f2bf(v.w);
    reinterpret_cast<short4*>(dst)[i] = o;
  }
}

// fused fp32->bf16 + transpose: Wt[n][k] = W[k][n], for all four weights
__global__ __launch_bounds__(256) void cvt_t_kernel(
    const float* __restrict__ W0, const float* __restrict__ W1,
    const float* __restrict__ W2, const float* __restrict__ W3,
    short* __restrict__ T0, short* __restrict__ T1,
    short* __restrict__ T2, short* __restrict__ T3) {
  const float* W = blockIdx.z == 0 ? W0 : blockIdx.z == 1 ? W1 : blockIdx.z == 2 ? W2 : W3;
  short* Wt = blockIdx.z == 0 ? T0 : blockIdx.z == 1 ? T1 : blockIdx.z == 2 ? T2 : T3;
  __shared__ __align__(16) short T[64 * 72];
  const int tid = threadIdx.x;
  const int k0 = blockIdx.y * 64, n0 = blockIdx.x * 64;
#pragma unroll
  for (int p = 0; p < 4; ++p) {
    int idx = tid + p * 256;
    int kr = idx >> 4, c4 = (idx & 15) * 4;
    float4 v = *reinterpret_cast<const float4*>(W + (size_t)(k0 + kr) * Dm + n0 + c4);
    T[(c4 + 0) * 72 + kr] = (short)f2bf(v.x);
    T[(c4 + 1) * 72 + kr] = (short)f2bf(v.y);
    T[(c4 + 2) * 72 + kr] = (short)f2bf(v.z);
    T[(c4 + 3) * 72 + kr] = (short)f2bf(v.w);
  }
  __syncthreads();
#pragma unroll
  for (int p = 0; p < 2; ++p) {
    int idx = tid + p * 256;
    int nr = idx >> 3, c8 = (idx & 7) * 8;
    *reinterpret_cast<short8*>(Wt + (size_t)(n0 + nr) * Dm + k0 + c8) =
        *reinterpret_cast<const short8*>(&T[nr * 72 + c8]);
  }
}

// ---------------- Wave-autonomous GEMM (NO barriers in main loop) -----------
// Each WAVE owns a 64x64 output tile with PRIVATE LDS staging (A 4KB + B 4KB
// per buffer, 2 buffers = 16KB/wave). Sync = the wave's own counted vmcnt(8)
// only (stage kt+1's 8 global_load_lds, wait tile kt's 8). No cross-wave
// hazards (private LDS regions); ds_read->MFMA ordering is compiler lgkmcnt.
// Source chunk-swizzle (rule #21, r9-verified): LDS(row,c) holds global chunk
// c ^ ((row>>1)&3); reads use chunk g ^ ((lr>>1)&3) -> conflict-free b128.
// Block = 2 waves (128 thr), 32KB LDS -> 5 blocks/CU = 10 independent waves.
// MODE 0: fused QKV epilogue (z = n0g>>10); MODE 1: out-proj fp32 + bias.
template <int MODE>
__global__ __launch_bounds__(128, 4) void gemm_wave_kernel(
    const short* __restrict__ Ags, const short* __restrict__ Bts,
    short* __restrict__ Qo, short* __restrict__ Ko, short* __restrict__ Vo,
    float* __restrict__ Cf, const float* __restrict__ bias) {
  __shared__ __align__(16) short L[2][2][2][64 * 32];  // [wave][buf][mat][4KB]
  constexpr int NT = Dm / 32;  // 32 K-steps
  const int tid = threadIdx.x;
  const int lane = tid & 63;
  const int w = tid >> 6;
  const int g = lane >> 4;
  const int lr = lane & 15;
  const int m0 = blockIdx.x * 128 + w * 64;  // wave's 64 output rows
  const int n0g = blockIdx.y * 64;           // wave-col == block-col
  // staging: gload j covers rows j*16..j*16+15; lane -> row j*16+(lane>>2),
  // chunk (lane&3) ^ ((lane>>3)&3)  [= c ^ ((row>>1)&3), j*16 even multiple]
  const int srow = lane >> 2;
  const int sch = ((lane & 3) ^ ((lane >> 3) & 3)) * 8;
  const short* Asrc[4];
  const short* Bsrc[4];
#pragma unroll
  for (int j = 0; j < 4; ++j) {
    Asrc[j] = Ags + (size_t)(m0 + j * 16 + srow) * Dm + sch;
    Bsrc[j] = Bts + (size_t)(n0g + j * 16 + srow) * Dm + sch;
  }

  auto stage = [&](int kt, int buf) {
#pragma unroll
    for (int j = 0; j < 4; ++j) {
      gload16(Asrc[j] + kt * 32, &L[w][buf][0][j * 512]);
      gload16(Bsrc[j] + kt * 32, &L[w][buf][1][j * 512]);
    }
  };

  f32x4 acc[4][4];
#pragma unroll
  for (int mi = 0; mi < 4; ++mi)
#pragma unroll
    for (int ni = 0; ni < 4; ++ni)
#pragma unroll
      for (int r = 0; r < 4; ++r) acc[mi][ni][r] = 0.f;

  const int csel = (g ^ ((lr >> 1) & 3)) * 8;

  stage(0, 0);
  for (int kt = 0; kt < NT; ++kt) {
    if (kt + 1 < NT) {
      stage(kt + 1, (kt + 1) & 1);
      __builtin_amdgcn_sched_barrier(0);
      asm volatile("s_waitcnt vmcnt(8)" ::: "memory");  // retire tile-kt loads
    } else {
      asm volatile("s_waitcnt vmcnt(0)" ::: "memory");
    }
    __builtin_amdgcn_sched_barrier(0);
    const int cur = kt & 1;
    short8 a[4], b[4];
#pragma unroll
    for (int mi = 0; mi < 4; ++mi)
      a[mi] = *reinterpret_cast<const short8*>(
          &L[w][cur][0][(mi * 16 + lr) * 32 + csel]);
#pragma unroll
    for (int ni = 0; ni < 4; ++ni)
      b[ni] = *reinterpret_cast<const short8*>(
          &L[w][cur][1][(ni * 16 + lr) * 32 + csel]);
#pragma unroll
    for (int mi = 0; mi < 4; ++mi)
#pragma unroll
      for (int ni = 0; ni < 4; ++ni)
        acc[mi][ni] = MFMA_BF16(a[mi], b[ni], acc[mi][ni], 0, 0, 0);
  }

  // epilogue
  const int z = n0g >> 10;
  const int n0 = n0g & 1023;
  short* Co = (MODE == 0) ? (z == 0 ? Qo : z == 1 ? Ko : Vo) : nullptr;
#pragma unroll
  for (int mi = 0; mi < 4; ++mi)
#pragma unroll
    for (int ni = 0; ni < 4; ++ni)
#pragma unroll
      for (int r = 0; r < 4; ++r) {
        int mg = m0 + mi * 16 + g * 4 + r;  // C/D: row=(lane>>4)*4+reg
        float v = acc[mi][ni][r];
        if (MODE == 1) {
          int ng = n0g + ni * 16 + lr;
          Cf[(size_t)mg * Dm + ng] = v + bias[ng];
        } else {
          int ng = n0 + ni * 16 + lr;  // col within 1024
          int b_ = mg >> 11, t_ = mg & 2047, h_ = ng >> 6, d_ = ng & 63;
          size_t bh = (size_t)(b_ * NHm + h_);
          if (z == 0) {
            Co[(bh * Tm + t_) * HDm + d_] = (short)f2bf(v * kQScale);
          } else if (z == 1) {
            Co[((bh * NKT + (t_ >> 6)) << 12) + (t_ & 63) * 64 + (d_ ^ ((t_ & 7) << 3))] =
                (short)f2bf(v);
          } else {
            Co[((bh * NKT + (t_ >> 6)) << 12) + d_ * 64 + ((t_ & 63) ^ ((d_ & 7) << 3))] =
                (short)f2bf(v);
          }
        }
      }
}

// Flash attention (unchanged r9): causal, fixed-offset softmax, l via
// ones-MFMA, 3-buffer 2-deep prefetch with counted vmcnt, XCD-local grid.
__global__ __launch_bounds__(256) void attn_kernel(
    const short* __restrict__ Qg, const short* __restrict__ Kg,
    const short* __restrict__ Vg, short* __restrict__ Og) {
  __shared__ __align__(16) short Kl[3][64 * 64];
  __shared__ __align__(16) short Vl[3][64 * 64];
  __shared__ __align__(16) short Pl[4][32 * 72];
  const int tid = threadIdx.x;
  const int lane = tid & 63;
  const int w = tid >> 6;
  const int g = lane >> 4;
  const int lr = lane & 15;
  const int bh = blockIdx.x;
  const int pi = blockIdx.y;
  const short* Ks = Kg + ((size_t)bh * NKT << 12);
  const short* Vs = Vg + ((size_t)bh * NKT << 12);
  short* Pw = &Pl[w][0];
  const int b_ = bh >> 4, h_ = bh & 15;

  short8 ones;
#pragma unroll
  for (int j = 0; j < 8; ++j) ones[j] = (short)0x3F80;  // bf16 1.0

  auto stage = [&](int t, int buf) {
#pragma unroll
    for (int i = 0; i < 2; ++i) {
      int ch = w * 2 + i;
      gload16(Ks + ((size_t)t << 12) + ch * 512 + lane * 8, &Kl[buf][ch * 512]);
      gload16(Vs + ((size_t)t << 12) + ch * 512 + lane * 8, &Vl[buf][ch * 512]);
    }
  };

  for (int pass = 0; pass < 2; ++pass) {
    const int qb = pass == 0 ? (15 - pi) : pi;
    const int q0 = qb * 128;
    const int qw = q0 + w * 32;
    const short* Qs = Qg + ((size_t)bh * Tm + q0) * HDm;

    short8 qf[2][2];
#pragma unroll
    for (int mi = 0; mi < 2; ++mi)
#pragma unroll
      for (int kk = 0; kk < 2; ++kk)
        qf[mi][kk] = *reinterpret_cast<const short8*>(
            Qs + (w * 32 + mi * 16 + lr) * HDm + kk * 32 + g * 8);

    f32x4 o[2][4], lacc[2];
#pragma unroll
    for (int mi = 0; mi < 2; ++mi)
#pragma unroll
      for (int r = 0; r < 4; ++r) {
        lacc[mi][r] = 0.f;
#pragma unroll
        for (int di = 0; di < 4; ++di) o[mi][di][r] = 0.f;
      }

    const int nt = q0 / 64 + 2;
    stage(0, 0);
    stage(1, 1);
    for (int t = 0; t < nt; ++t) {
      if (t < nt - 1) asm volatile("s_waitcnt vmcnt(4)" ::: "memory");
      else            asm volatile("s_waitcnt vmcnt(0)" ::: "memory");
      __builtin_amdgcn_s_barrier();
      __builtin_amdgcn_sched_barrier(0);
      if (t + 2 < nt) stage(t + 2, (t + 2) % 3);
      const int cur = t % 3;
      const int k0 = t * 64;
      const bool active = (k0 <= qw + 31);
      if (active) {
        short8 kf[2][4];
#pragma unroll
        for (int ni = 0; ni < 4; ++ni) {
          int row = ni * 16 + lr;
#pragma unroll
          for (int kk = 0; kk < 2; ++kk)
            kf[kk][ni] = *reinterpret_cast<const short8*>(
                &Kl[cur][row * 64 + ((kk * 32 + g * 8) ^ ((row & 7) << 3))]);
        }
        f32x4 s[2][4];
#pragma unroll
        for (int mi = 0; mi < 2; ++mi)
#pragma unroll
          for (int ni = 0; ni < 4; ++ni) {
            f32x4 acc;
#pragma unroll
            for (int r = 0; r < 4; ++r) acc[r] = 0.f;
            acc = MFMA_BF16(qf[mi][0], kf[0][ni], acc, 0, 0, 0);
            acc = MFMA_BF16(qf[mi][1], kf[1][ni], acc, 0, 0, 0);
            s[mi][ni] = acc;
          }
        if (k0 + 63 > qw) {
#pragma unroll
          for (int mi = 0; mi < 2; ++mi)
#pragma unroll
            for (int ni = 0; ni < 4; ++ni)
#pragma unroll
              for (int r = 0; r < 4; ++r)
                if (k0 + ni * 16 + lr > qw + mi * 16 + g * 4 + r) s[mi][ni][r] = -1e30f;
        }
#pragma unroll
        for (int mi = 0; mi < 2; ++mi)
#pragma unroll
          for (int ni = 0; ni < 4; ++ni)
#pragma unroll
            for (int r = 0; r < 4; ++r)
              Pw[(mi * 16 + g * 4 + r) * 72 + ((ni * 16 + lr) ^ (g << 4))] =
                  (short)f2bf(fexp2(s[mi][ni][r]));

#pragma unroll
        for (int kk = 0; kk < 2; ++kk) {
          short8 pf[2];
#pragma unroll
          for (int mi = 0; mi < 2; ++mi)
            pf[mi] = *reinterpret_cast<const short8*>(
                &Pw[(mi * 16 + lr) * 72 + ((kk * 32 + g * 8) ^ ((lr >> 2) << 4))]);
#pragma unroll
          for (int mi = 0; mi < 2; ++mi)
            lacc[mi] = MFMA_BF16(pf[mi], ones, lacc[mi], 0, 0, 0);
#pragma unroll
          for (int di = 0; di < 4; ++di) {
            int d = di * 16 + lr;
            short8 vf = *reinterpret_cast<const short8*>(
                &Vl[cur][d * 64 + ((kk * 32 + g * 8) ^ ((d & 7) << 3))]);
#pragma unroll
            for (int mi = 0; mi < 2; ++mi)
              o[mi][di] = MFMA_BF16(pf[mi], vf, o[mi][di], 0, 0, 0);
          }
        }
      }
    }
    __syncthreads();

#pragma unroll
    for (int mi = 0; mi < 2; ++mi)
#pragma unroll
      for (int di = 0; di < 4; ++di)
#pragma unroll
        for (int r = 0; r < 4; ++r) {
          float ov = o[mi][di][r] / lacc[mi][r];
          int qg = q0 + w * 32 + mi * 16 + g * 4 + r;
          int d_ = di * 16 + lr;
          Og[((size_t)b_ * Tm + qg) * Dm + h_ * HDm + d_] = (short)f2bf(ov);
        }
  }
}

extern "C" void kernel_launch(void* const* d_in, const int* in_sizes, int n_in,
                              void* d_out, int out_size, void* d_ws, size_t ws_size,
                              hipStream_t stream) {
  const float* X = (const float*)d_in[0];
  const float* Wq = (const float*)d_in[1];
  const float* Wk = (const float*)d_in[2];
  const float* Wv = (const float*)d_in[3];
  const float* Wo = (const float*)d_in[4];
  const float* bo = (const float*)d_in[5];
  float* out = (float*)d_out;

  char* ws = (char*)d_ws;
  short* Xb = (short*)ws;  ws += (size_t)Mtot * Dm * 2;
  short* Wqt = (short*)ws; ws += (size_t)Dm * Dm * 2;  // [3072][1024] contiguous
  short* Wkt = (short*)ws; ws += (size_t)Dm * Dm * 2;
  short* Wvt = (short*)ws; ws += (size_t)Dm * Dm * 2;
  short* Wot = (short*)ws; ws += (size_t)Dm * Dm * 2;
  short* Qb = (short*)ws;  ws += (size_t)Mtot * Dm * 2;
  short* Kb = (short*)ws;  ws += (size_t)Mtot * Dm * 2;
  short* Vb = (short*)ws;  ws += (size_t)Mtot * Dm * 2;
  short* Ab = (short*)ws;  ws += (size_t)Mtot * Dm * 2;

  cvt_kernel<<<dim3(1024), dim3(256), 0, stream>>>(X, Xb, Mtot * Dm);
  cvt_t_kernel<<<dim3(16, 16, 4), dim3(256), 0, stream>>>(Wq, Wk, Wv, Wo, Wqt, Wkt, Wvt, Wot);

  gemm_wave_kernel<0><<<dim3(Mtot / 128, 3 * Dm / 64), 128, 0, stream>>>(
      Xb, Wqt, Qb, Kb, Vb, nullptr, nullptr);

  attn_kernel<<<dim3(Bb * NHm, 8), 256, 0, stream>>>(Qb, Kb, Vb, Ab);

  gemm_wave_kernel<1><<<dim3(Mtot / 128, Dm / 64), 128, 0, stream>>>(
      Ab, Wot, nullptr, nullptr, nullptr, out, bo);
}

// Round 13
// 189.221 us; speedup vs baseline: 1.5340x; 1.2080x over previous
//
#include <hip/hip_runtime.h>
#include <hip/hip_bf16.h>
#include <math.h>

typedef __attribute__((ext_vector_type(8))) short short8;
typedef __attribute__((ext_vector_type(4))) float f32x4;

#define MFMA_BF16 __builtin_amdgcn_mfma_f32_16x16x32_bf16

static constexpr int Dm = 1024;
static constexpr int Tm = 2048;
static constexpr int Bb = 4;
static constexpr int NHm = 16;
static constexpr int HDm = 64;
static constexpr int Mtot = Bb * Tm;   // 8192
static constexpr int NKT = Tm / 64;    // 32 KV tiles per (b,h)
static constexpr float kQScale = 0.125f * 1.4426950408889634f;  // 1/sqrt(64) * log2(e)

__device__ __forceinline__ unsigned short f2bf(float f) {
  unsigned int u = __float_as_uint(f);
  u += 0x7FFFu + ((u >> 16) & 1u);  // RNE
  return (unsigned short)(u >> 16);
}

__device__ __forceinline__ float fexp2(float x) {  // raw v_exp_f32 (2^x)
  float r;
  asm("v_exp_f32 %0, %1" : "=v"(r) : "v"(x));
  return r;
}

__device__ __forceinline__ void gload16(const void* g, void* l) {
  __builtin_amdgcn_global_load_lds((const __attribute__((address_space(1))) void*)g,
                                   (__attribute__((address_space(3))) void*)l, 16, 0, 0);
}

// Fused conversion kernel (one launch): z<4 -> weight fp32->bf16 + transpose
// (Wt[n][k] = W[k][n]); z==4 -> X fp32->bf16 grid-stride convert.
__global__ __launch_bounds__(256) void cvt_all_kernel(
    const float* __restrict__ X, const float* __restrict__ W0,
    const float* __restrict__ W1, const float* __restrict__ W2,
    const float* __restrict__ W3, short* __restrict__ Xb,
    short* __restrict__ T0, short* __restrict__ T1,
    short* __restrict__ T2, short* __restrict__ T3) {
  const int tid = threadIdx.x;
  if (blockIdx.z == 4) {
    // X: 8.4M elems = 2.1M float4; 256 blocks x 256 threads -> 32 iters/thread
    const int stride = 16 * 16 * 256;
    for (int i = (blockIdx.y * 16 + blockIdx.x) * 256 + tid; i < Mtot * Dm / 4;
         i += stride) {
      float4 v = reinterpret_cast<const float4*>(X)[i];
      short4 o;
      o.x = (short)f2bf(v.x);
      o.y = (short)f2bf(v.y);
      o.z = (short)f2bf(v.z);
      o.w = (short)f2bf(v.w);
      reinterpret_cast<short4*>(Xb)[i] = o;
    }
    return;
  }
  const float* W = blockIdx.z == 0 ? W0 : blockIdx.z == 1 ? W1 : blockIdx.z == 2 ? W2 : W3;
  short* Wt = blockIdx.z == 0 ? T0 : blockIdx.z == 1 ? T1 : blockIdx.z == 2 ? T2 : T3;
  __shared__ __align__(16) short T[64 * 72];
  const int k0 = blockIdx.y * 64, n0 = blockIdx.x * 64;
#pragma unroll
  for (int p = 0; p < 4; ++p) {
    int idx = tid + p * 256;
    int kr = idx >> 4, c4 = (idx & 15) * 4;
    float4 v = *reinterpret_cast<const float4*>(W + (size_t)(k0 + kr) * Dm + n0 + c4);
    T[(c4 + 0) * 72 + kr] = (short)f2bf(v.x);
    T[(c4 + 1) * 72 + kr] = (short)f2bf(v.y);
    T[(c4 + 2) * 72 + kr] = (short)f2bf(v.z);
    T[(c4 + 3) * 72 + kr] = (short)f2bf(v.w);
  }
  __syncthreads();
#pragma unroll
  for (int p = 0; p < 2; ++p) {
    int idx = tid + p * 256;
    int nr = idx >> 3, c8 = (idx & 7) * 8;
    *reinterpret_cast<short8*>(Wt + (size_t)(n0 + nr) * Dm + k0 + c8) =
        *reinterpret_cast<const short8*>(&T[nr * 72 + c8]);
  }
}

// Hybrid 2-phase 128x128/BK=32 mainloop (r9, best-measured): 2 LDS buffers
// (32 KB -> 4 blocks/CU at VGPR 72) + counted vmcnt so the barrier never
// drains the fresh prefetch. At the wait: outstanding = 4 (tile kt) + 4
// (tile kt+1) -> vmcnt(4) retires exactly tile kt. Last iteration drains.
// LDS chunk-swizzle (verified 0 conflicts): LDS(r,c16) holds global chunk
// c16 ^ ((r>>1)&3), applied on the global SOURCE address (rule #21);
// fragment reads use chunk (g ^ ((lr>>1)&3)) -> 2 lanes/bank = free.
__device__ __forceinline__ void gemm_mainloop3(
    const short* __restrict__ A, const short* __restrict__ B,
    int m0, int n0, short* As, short* Bs, f32x4 acc[4][4], int tid) {
  const int lane = tid & 63;
  const int w = tid >> 6;
  const int wr = (w >> 1) * 64, wc = (w & 1) * 64;
  const int lr = lane & 15;
  const int g = lane >> 4;
  const int rowt = tid >> 2;
  const int csw = ((tid & 3) ^ ((tid >> 3) & 3)) * 8;

  const short* A0 = A + (size_t)(m0 + rowt) * Dm + csw;
  const short* A1 = A + (size_t)(m0 + 64 + rowt) * Dm + csw;
  const short* B0 = B + (size_t)(n0 + rowt) * Dm + csw;
  const short* B1 = B + (size_t)(n0 + 64 + rowt) * Dm + csw;
  short* Ad0 = As + (w * 16) * 32;
  short* Ad1 = As + (64 + w * 16) * 32;
  short* Bd0 = Bs + (w * 16) * 32;
  short* Bd1 = Bs + (64 + w * 16) * 32;

  auto stage = [&](int kt, int buf) {
    const int ko = kt * 32;
    gload16(A0 + ko, Ad0 + buf * 4096);
    gload16(A1 + ko, Ad1 + buf * 4096);
    gload16(B0 + ko, Bd0 + buf * 4096);
    gload16(B1 + ko, Bd1 + buf * 4096);
  };

  const int csel = (g ^ ((lr >> 1) & 3)) * 8;

  stage(0, 0);
  for (int kt = 0; kt < Dm / 32; ++kt) {
    __builtin_amdgcn_s_barrier();  // prior iteration's readers of dst buf done
    if (kt + 1 < Dm / 32) {
      stage(kt + 1, (kt + 1) & 1);
      __builtin_amdgcn_sched_barrier(0);
      asm volatile("s_waitcnt vmcnt(4)" ::: "memory");  // tile-kt loads only
    } else {
      asm volatile("s_waitcnt vmcnt(0)" ::: "memory");
    }
    __builtin_amdgcn_s_barrier();  // publish tile-kt LDS to all waves
    __builtin_amdgcn_sched_barrier(0);
    const int cur = kt & 1;
    short8 a[4], b[4];
#pragma unroll
    for (int mi = 0; mi < 4; ++mi)
      a[mi] = *reinterpret_cast<const short8*>(
          &As[cur * 4096 + (wr + mi * 16 + lr) * 32 + csel]);
#pragma unroll
    for (int ni = 0; ni < 4; ++ni)
      b[ni] = *reinterpret_cast<const short8*>(
          &Bs[cur * 4096 + (wc + ni * 16 + lr) * 32 + csel]);
#pragma unroll
    for (int mi = 0; mi < 4; ++mi)
#pragma unroll
      for (int ni = 0; ni < 4; ++ni)
        acc[mi][ni] = MFMA_BF16(a[mi], b[ni], acc[mi][ni], 0, 0, 0);
  }
}

// Fused QKV as ONE GEMM: A(8192x1024) @ WT3^T, WT3 = [Wq;Wk;Wv]^T [3072][1024].
// grid = (m=64, n=24): same-m blocks have id%8 == m%8 -> same XCD L2.
__global__ __launch_bounds__(256) void gemm_qkv_kernel(
    const short* __restrict__ Ags, const short* __restrict__ WT3,
    short* __restrict__ Qo, short* __restrict__ Ko, short* __restrict__ Vo) {
  __shared__ __align__(16) short As[2 * 128 * 32];
  __shared__ __align__(16) short Bs[2 * 128 * 32];
  const int tid = threadIdx.x;
  const int m0 = blockIdx.x * 128;
  const int n0g = blockIdx.y * 128;  // 0..3071
  const int z = n0g >> 10;
  const int n0 = n0g & 1023;
  short* Co = z == 0 ? Qo : z == 1 ? Ko : Vo;

  f32x4 acc[4][4];
#pragma unroll
  for (int mi = 0; mi < 4; ++mi)
#pragma unroll
    for (int ni = 0; ni < 4; ++ni)
#pragma unroll
      for (int r = 0; r < 4; ++r) acc[mi][ni][r] = 0.f;

  gemm_mainloop3(Ags, WT3, m0, n0g, As, Bs, acc, tid);

  const int lane = tid & 63;
  const int w = tid >> 6;
  const int wr = (w >> 1) * 64, wc = (w & 1) * 64;
  const int g = lane >> 4, lr = lane & 15;
#pragma unroll
  for (int mi = 0; mi < 4; ++mi)
#pragma unroll
    for (int ni = 0; ni < 4; ++ni)
#pragma unroll
      for (int r = 0; r < 4; ++r) {
        int mg = m0 + wr + mi * 16 + g * 4 + r;  // C/D: row=(lane>>4)*4+reg
        int ng = n0 + wc + ni * 16 + lr;         // C/D: col=lane&15
        float v = acc[mi][ni][r];
        int b_ = mg >> 11, t_ = mg & 2047, h_ = ng >> 6, d_ = ng & 63;
        size_t bh = (size_t)(b_ * NHm + h_);
        if (z == 0) {
          Co[(bh * Tm + t_) * HDm + d_] = (short)f2bf(v * kQScale);
        } else if (z == 1) {
          Co[((bh * NKT + (t_ >> 6)) << 12) + (t_ & 63) * 64 + (d_ ^ ((t_ & 7) << 3))] =
              (short)f2bf(v);
        } else {
          Co[((bh * NKT + (t_ >> 6)) << 12) + d_ * 64 + ((t_ & 63) ^ ((d_ & 7) << 3))] =
              (short)f2bf(v);
        }
      }
}

// Out-projection: fp32 + bias, row-major. grid = (m=64, n=8) = 512 blocks.
__global__ __launch_bounds__(256) void gemm_out_kernel(
    const short* __restrict__ Ags, const short* __restrict__ Bts,
    float* __restrict__ Cf, const float* __restrict__ bias) {
  __shared__ __align__(16) short As[2 * 128 * 32];
  __shared__ __align__(16) short Bs[2 * 128 * 32];
  const int tid = threadIdx.x;
  const int m0 = blockIdx.x * 128;
  const int n0 = blockIdx.y * 128;

  f32x4 acc[4][4];
#pragma unroll
  for (int mi = 0; mi < 4; ++mi)
#pragma unroll
    for (int ni = 0; ni < 4; ++ni)
#pragma unroll
      for (int r = 0; r < 4; ++r) acc[mi][ni][r] = 0.f;

  gemm_mainloop3(Ags, Bts, m0, n0, As, Bs, acc, tid);

  const int lane = tid & 63;
  const int w = tid >> 6;
  const int wr = (w >> 1) * 64, wc = (w & 1) * 64;
  const int g = lane >> 4, lr = lane & 15;
#pragma unroll
  for (int mi = 0; mi < 4; ++mi)
#pragma unroll
    for (int ni = 0; ni < 4; ++ni)
#pragma unroll
      for (int r = 0; r < 4; ++r) {
        int mg = m0 + wr + mi * 16 + g * 4 + r;
        int ng = n0 + wc + ni * 16 + lr;
        Cf[(size_t)mg * Dm + ng] = acc[mi][ni][r] + bias[ng];
      }
}

// Flash attention (r9 structure + T5 setprio on MFMA clusters): causal,
// fixed-offset softmax, l via ones-MFMA, 3-buffer 2-deep prefetch with
// counted vmcnt, XCD-local grid.
__global__ __launch_bounds__(256) void attn_kernel(
    const short* __restrict__ Qg, const short* __restrict__ Kg,
    const short* __restrict__ Vg, short* __restrict__ Og) {
  __shared__ __align__(16) short Kl[3][64 * 64];
  __shared__ __align__(16) short Vl[3][64 * 64];
  __shared__ __align__(16) short Pl[4][32 * 72];
  const int tid = threadIdx.x;
  const int lane = tid & 63;
  const int w = tid >> 6;
  const int g = lane >> 4;
  const int lr = lane & 15;
  const int bh = blockIdx.x;
  const int pi = blockIdx.y;
  const short* Ks = Kg + ((size_t)bh * NKT << 12);
  const short* Vs = Vg + ((size_t)bh * NKT << 12);
  short* Pw = &Pl[w][0];
  const int b_ = bh >> 4, h_ = bh & 15;

  short8 ones;
#pragma unroll
  for (int j = 0; j < 8; ++j) ones[j] = (short)0x3F80;  // bf16 1.0

  auto stage = [&](int t, int buf) {
#pragma unroll
    for (int i = 0; i < 2; ++i) {
      int ch = w * 2 + i;
      gload16(Ks + ((size_t)t << 12) + ch * 512 + lane * 8, &Kl[buf][ch * 512]);
      gload16(Vs + ((size_t)t << 12) + ch * 512 + lane * 8, &Vl[buf][ch * 512]);
    }
  };

  for (int pass = 0; pass < 2; ++pass) {
    const int qb = pass == 0 ? (15 - pi) : pi;
    const int q0 = qb * 128;
    const int qw = q0 + w * 32;
    const short* Qs = Qg + ((size_t)bh * Tm + q0) * HDm;

    short8 qf[2][2];
#pragma unroll
    for (int mi = 0; mi < 2; ++mi)
#pragma unroll
      for (int kk = 0; kk < 2; ++kk)
        qf[mi][kk] = *reinterpret_cast<const short8*>(
            Qs + (w * 32 + mi * 16 + lr) * HDm + kk * 32 + g * 8);

    f32x4 o[2][4], lacc[2];
#pragma unroll
    for (int mi = 0; mi < 2; ++mi)
#pragma unroll
      for (int r = 0; r < 4; ++r) {
        lacc[mi][r] = 0.f;
#pragma unroll
        for (int di = 0; di < 4; ++di) o[mi][di][r] = 0.f;
      }

    const int nt = q0 / 64 + 2;
    stage(0, 0);
    stage(1, 1);
    for (int t = 0; t < nt; ++t) {
      if (t < nt - 1) asm volatile("s_waitcnt vmcnt(4)" ::: "memory");
      else            asm volatile("s_waitcnt vmcnt(0)" ::: "memory");
      __builtin_amdgcn_s_barrier();
      __builtin_amdgcn_sched_barrier(0);
      if (t + 2 < nt) stage(t + 2, (t + 2) % 3);
      const int cur = t % 3;
      const int k0 = t * 64;
      const bool active = (k0 <= qw + 31);
      if (active) {
        short8 kf[2][4];
#pragma unroll
        for (int ni = 0; ni < 4; ++ni) {
          int row = ni * 16 + lr;
#pragma unroll
          for (int kk = 0; kk < 2; ++kk)
            kf[kk][ni] = *reinterpret_cast<const short8*>(
                &Kl[cur][row * 64 + ((kk * 32 + g * 8) ^ ((row & 7) << 3))]);
        }
        f32x4 s[2][4];
        __builtin_amdgcn_s_setprio(1);  // T5: favor QK^T MFMA cluster
#pragma unroll
        for (int mi = 0; mi < 2; ++mi)
#pragma unroll
          for (int ni = 0; ni < 4; ++ni) {
            f32x4 acc;
#pragma unroll
            for (int r = 0; r < 4; ++r) acc[r] = 0.f;
            acc = MFMA_BF16(qf[mi][0], kf[0][ni], acc, 0, 0, 0);
            acc = MFMA_BF16(qf[mi][1], kf[1][ni], acc, 0, 0, 0);
            s[mi][ni] = acc;
          }
        __builtin_amdgcn_s_setprio(0);
        if (k0 + 63 > qw) {
#pragma unroll
          for (int mi = 0; mi < 2; ++mi)
#pragma unroll
            for (int ni = 0; ni < 4; ++ni)
#pragma unroll
              for (int r = 0; r < 4; ++r)
                if (k0 + ni * 16 + lr > qw + mi * 16 + g * 4 + r) s[mi][ni][r] = -1e30f;
        }
#pragma unroll
        for (int mi = 0; mi < 2; ++mi)
#pragma unroll
          for (int ni = 0; ni < 4; ++ni)
#pragma unroll
            for (int r = 0; r < 4; ++r)
              Pw[(mi * 16 + g * 4 + r) * 72 + ((ni * 16 + lr) ^ (g << 4))] =
                  (short)f2bf(fexp2(s[mi][ni][r]));

        __builtin_amdgcn_s_setprio(1);  // T5: favor PV MFMA cluster
#pragma unroll
        for (int kk = 0; kk < 2; ++kk) {
          short8 pf[2];
#pragma unroll
          for (int mi = 0; mi < 2; ++mi)
            pf[mi] = *reinterpret_cast<const short8*>(
                &Pw[(mi * 16 + lr) * 72 + ((kk * 32 + g * 8) ^ ((lr >> 2) << 4))]);
#pragma unroll
          for (int mi = 0; mi < 2; ++mi)
            lacc[mi] = MFMA_BF16(pf[mi], ones, lacc[mi], 0, 0, 0);
#pragma unroll
          for (int di = 0; di < 4; ++di) {
            int d = di * 16 + lr;
            short8 vf = *reinterpret_cast<const short8*>(
                &Vl[cur][d * 64 + ((kk * 32 + g * 8) ^ ((d & 7) << 3))]);
#pragma unroll
            for (int mi = 0; mi < 2; ++mi)
              o[mi][di] = MFMA_BF16(pf[mi], vf, o[mi][di], 0, 0, 0);
          }
        }
        __builtin_amdgcn_s_setprio(0);
      }
    }
    __syncthreads();

#pragma unroll
    for (int mi = 0; mi < 2; ++mi)
#pragma unroll
      for (int di = 0; di < 4; ++di)
#pragma unroll
        for (int r = 0; r < 4; ++r) {
          float ov = o[mi][di][r] / lacc[mi][r];
          int qg = q0 + w * 32 + mi * 16 + g * 4 + r;
          int d_ = di * 16 + lr;
          Og[((size_t)b_ * Tm + qg) * Dm + h_ * HDm + d_] = (short)f2bf(ov);
        }
  }
}

extern "C" void kernel_launch(void* const* d_in, const int* in_sizes, int n_in,
                              void* d_out, int out_size, void* d_ws, size_t ws_size,
                              hipStream_t stream) {
  const float* X = (const float*)d_in[0];
  const float* Wq = (const float*)d_in[1];
  const float* Wk = (const float*)d_in[2];
  const float* Wv = (const float*)d_in[3];
  const float* Wo = (const float*)d_in[4];
  const float* bo = (const float*)d_in[5];
  float* out = (float*)d_out;

  char* ws = (char*)d_ws;
  short* Xb = (short*)ws;  ws += (size_t)Mtot * Dm * 2;
  short* Wqt = (short*)ws; ws += (size_t)Dm * Dm * 2;  // [3072][1024] contiguous
  short* Wkt = (short*)ws; ws += (size_t)Dm * Dm * 2;
  short* Wvt = (short*)ws; ws += (size_t)Dm * Dm * 2;
  short* Wot = (short*)ws; ws += (size_t)Dm * Dm * 2;
  short* Qb = (short*)ws;  ws += (size_t)Mtot * Dm * 2;
  short* Kb = (short*)ws;  ws += (size_t)Mtot * Dm * 2;
  short* Vb = (short*)ws;  ws += (size_t)Mtot * Dm * 2;
  short* Ab = (short*)ws;  ws += (size_t)Mtot * Dm * 2;

  cvt_all_kernel<<<dim3(16, 16, 5), 256, 0, stream>>>(
      X, Wq, Wk, Wv, Wo, Xb, Wqt, Wkt, Wvt, Wot);

  gemm_qkv_kernel<<<dim3(Mtot / 128, 3 * Dm / 128), 256, 0, stream>>>(
      Xb, Wqt, Qb, Kb, Vb);

  attn_kernel<<<dim3(Bb * NHm, 8), 256, 0, stream>>>(Qb, Kb, Vb, Ab);

  gemm_out_kernel<<<dim3(Mtot / 128, Dm / 128), 256, 0, stream>>>(Ab, Wot, out, bo);
}

// Round 14
// 185.458 us; speedup vs baseline: 1.5651x; 1.0203x over previous
//
#include <hip/hip_runtime.h>
#include <hip/hip_bf16.h>
#include <math.h>

typedef __attribute__((ext_vector_type(8))) short short8;
typedef __attribute__((ext_vector_type(4))) float f32x4;

#define MFMA_BF16 __builtin_amdgcn_mfma_f32_16x16x32_bf16

static constexpr int Dm = 1024;
static constexpr int Tm = 2048;
static constexpr int Bb = 4;
static constexpr int NHm = 16;
static constexpr int HDm = 64;
static constexpr int Mtot = Bb * Tm;   // 8192
static constexpr int NKT = Tm / 64;    // 32 KV tiles per (b,h)
static constexpr float kQScale = 0.125f * 1.4426950408889634f;  // 1/sqrt(64) * log2(e)

__device__ __forceinline__ unsigned short f2bf(float f) {
  unsigned int u = __float_as_uint(f);
  u += 0x7FFFu + ((u >> 16) & 1u);  // RNE
  return (unsigned short)(u >> 16);
}

__device__ __forceinline__ float fexp2(float x) {  // raw v_exp_f32 (2^x)
  float r;
  asm("v_exp_f32 %0, %1" : "=v"(r) : "v"(x));
  return r;
}

__device__ __forceinline__ void gload16(const void* g, void* l) {
  __builtin_amdgcn_global_load_lds((const __attribute__((address_space(1))) void*)g,
                                   (__attribute__((address_space(3))) void*)l, 16, 0, 0);
}

// Fused conversion kernel (one launch): z<4 -> weight fp32->bf16 + transpose
// (Wt[n][k] = W[k][n]); z==4 -> X fp32->bf16 grid-stride convert.
__global__ __launch_bounds__(256) void cvt_all_kernel(
    const float* __restrict__ X, const float* __restrict__ W0,
    const float* __restrict__ W1, const float* __restrict__ W2,
    const float* __restrict__ W3, short* __restrict__ Xb,
    short* __restrict__ T0, short* __restrict__ T1,
    short* __restrict__ T2, short* __restrict__ T3) {
  const int tid = threadIdx.x;
  if (blockIdx.z == 4) {
    const int stride = 16 * 16 * 256;
    for (int i = (blockIdx.y * 16 + blockIdx.x) * 256 + tid; i < Mtot * Dm / 4;
         i += stride) {
      float4 v = reinterpret_cast<const float4*>(X)[i];
      short4 o;
      o.x = (short)f2bf(v.x);
      o.y = (short)f2bf(v.y);
      o.z = (short)f2bf(v.z);
      o.w = (short)f2bf(v.w);
      reinterpret_cast<short4*>(Xb)[i] = o;
    }
    return;
  }
  const float* W = blockIdx.z == 0 ? W0 : blockIdx.z == 1 ? W1 : blockIdx.z == 2 ? W2 : W3;
  short* Wt = blockIdx.z == 0 ? T0 : blockIdx.z == 1 ? T1 : blockIdx.z == 2 ? T2 : T3;
  __shared__ __align__(16) short T[64 * 72];
  const int k0 = blockIdx.y * 64, n0 = blockIdx.x * 64;
#pragma unroll
  for (int p = 0; p < 4; ++p) {
    int idx = tid + p * 256;
    int kr = idx >> 4, c4 = (idx & 15) * 4;
    float4 v = *reinterpret_cast<const float4*>(W + (size_t)(k0 + kr) * Dm + n0 + c4);
    T[(c4 + 0) * 72 + kr] = (short)f2bf(v.x);
    T[(c4 + 1) * 72 + kr] = (short)f2bf(v.y);
    T[(c4 + 2) * 72 + kr] = (short)f2bf(v.z);
    T[(c4 + 3) * 72 + kr] = (short)f2bf(v.w);
  }
  __syncthreads();
#pragma unroll
  for (int p = 0; p < 2; ++p) {
    int idx = tid + p * 256;
    int nr = idx >> 3, c8 = (idx & 7) * 8;
    *reinterpret_cast<short8*>(Wt + (size_t)(n0 + nr) * Dm + k0 + c8) =
        *reinterpret_cast<const short8*>(&T[nr * 72 + c8]);
  }
}

// ---- QKV: 128x128 tile, BK=64 (half the barrier periods, 2x work each) ----
// Hypothesis: the ~925cy K-step wall is fixed per-period overhead (latency
// exposure + barrier straggle); halving period count amortizes it. Cost:
// LDS 64KB + ~150 VGPR -> 2 blocks/CU. Same sync skeleton as r9 (proven):
// barrier; stage(kt+1) [8 loads]; vmcnt(8) [retires exactly tile kt's 8 of
// the 16 outstanding]; barrier; compute 16 ds_read + 32 MFMA. Last drains.
// Swizzle re-derived for 128B row pitch: LDS(r, c16) holds global chunk
// c16 ^ (r&7) (source-side, rule #21); reads use chunk (kk*4+g) ^ (lr&7)
// -> 8 accesses/bank = LDS minimum, conflict-free.
__global__ __launch_bounds__(256) void gemm_qkv_kernel(
    const short* __restrict__ Ags, const short* __restrict__ WT3,
    short* __restrict__ Qo, short* __restrict__ Ko, short* __restrict__ Vo) {
  __shared__ __align__(16) short As[2 * 128 * 64];  // 32 KB
  __shared__ __align__(16) short Bs[2 * 128 * 64];  // 32 KB
  constexpr int NT = Dm / 64;  // 16 periods
  const int tid = threadIdx.x;
  const int lane = tid & 63;
  const int w = tid >> 6;
  const int wr = (w >> 1) * 64, wc = (w & 1) * 64;
  const int g = lane >> 4;
  const int lr = lane & 15;
  const int m0 = blockIdx.x * 128;
  const int n0g = blockIdx.y * 128;  // 0..3071
  const int z = n0g >> 10;
  const int n0 = n0g & 1023;
  short* Co = z == 0 ? Qo : z == 1 ? Ko : Vo;

  // staging: 128x64 tile = 16KB = 4 loads/thread; load j covers rows j*32..+31
  // thread -> row j*32 + (tid>>3), src chunk (tid&7) ^ ((tid>>3)&7)
  const int srow = tid >> 3;
  const int sch = ((tid & 7) ^ (srow & 7)) * 8;
  const short* Asrc[4];
  const short* Bsrc[4];
#pragma unroll
  for (int j = 0; j < 4; ++j) {
    Asrc[j] = Ags + (size_t)(m0 + j * 32 + srow) * Dm + sch;
    Bsrc[j] = WT3 + (size_t)(n0g + j * 32 + srow) * Dm + sch;
  }

  auto stage = [&](int kt, int buf) {
    const int ko = kt * 64;
#pragma unroll
    for (int j = 0; j < 4; ++j) {
      gload16(Asrc[j] + ko, &As[buf * 8192 + j * 2048 + tid * 8]);
      gload16(Bsrc[j] + ko, &Bs[buf * 8192 + j * 2048 + tid * 8]);
    }
  };

  f32x4 acc[4][4];
#pragma unroll
  for (int mi = 0; mi < 4; ++mi)
#pragma unroll
    for (int ni = 0; ni < 4; ++ni)
#pragma unroll
      for (int r = 0; r < 4; ++r) acc[mi][ni][r] = 0.f;

  stage(0, 0);
  for (int kt = 0; kt < NT; ++kt) {
    __builtin_amdgcn_s_barrier();  // prior readers of dst buffer done
    if (kt + 1 < NT) {
      stage(kt + 1, (kt + 1) & 1);
      __builtin_amdgcn_sched_barrier(0);
      asm volatile("s_waitcnt vmcnt(8)" ::: "memory");  // retire tile kt only
    } else {
      asm volatile("s_waitcnt vmcnt(0)" ::: "memory");
    }
    __builtin_amdgcn_s_barrier();  // publish tile-kt LDS
    __builtin_amdgcn_sched_barrier(0);
    const int cur = kt & 1;
    short8 a[4][2], b[4][2];
#pragma unroll
    for (int mi = 0; mi < 4; ++mi) {
      const int row = wr + mi * 16 + lr;
#pragma unroll
      for (int kk = 0; kk < 2; ++kk)
        a[mi][kk] = *reinterpret_cast<const short8*>(
            &As[cur * 8192 + row * 64 + (((kk * 4 + g) ^ (lr & 7)) * 8)]);
    }
#pragma unroll
    for (int ni = 0; ni < 4; ++ni) {
      const int row = wc + ni * 16 + lr;
#pragma unroll
      for (int kk = 0; kk < 2; ++kk)
        b[ni][kk] = *reinterpret_cast<const short8*>(
            &Bs[cur * 8192 + row * 64 + (((kk * 4 + g) ^ (lr & 7)) * 8)]);
    }
#pragma unroll
    for (int kk = 0; kk < 2; ++kk)
#pragma unroll
      for (int mi = 0; mi < 4; ++mi)
#pragma unroll
        for (int ni = 0; ni < 4; ++ni)
          acc[mi][ni] = MFMA_BF16(a[mi][kk], b[ni][kk], acc[mi][ni], 0, 0, 0);
  }

#pragma unroll
  for (int mi = 0; mi < 4; ++mi)
#pragma unroll
    for (int ni = 0; ni < 4; ++ni)
#pragma unroll
      for (int r = 0; r < 4; ++r) {
        int mg = m0 + wr + mi * 16 + g * 4 + r;  // C/D: row=(lane>>4)*4+reg
        int ng = n0 + wc + ni * 16 + lr;         // C/D: col=lane&15
        float v = acc[mi][ni][r];
        int b_ = mg >> 11, t_ = mg & 2047, h_ = ng >> 6, d_ = ng & 63;
        size_t bh = (size_t)(b_ * NHm + h_);
        if (z == 0) {
          Co[(bh * Tm + t_) * HDm + d_] = (short)f2bf(v * kQScale);
        } else if (z == 1) {
          Co[((bh * NKT + (t_ >> 6)) << 12) + (t_ & 63) * 64 + (d_ ^ ((t_ & 7) << 3))] =
              (short)f2bf(v);
        } else {
          Co[((bh * NKT + (t_ >> 6)) << 12) + d_ * 64 + ((t_ & 63) ^ ((d_ & 7) << 3))] =
              (short)f2bf(v);
        }
      }
}

// -------- Out-proj: CONTROL — r9/r13 128x128 BK=32 structure, unchanged -----
__device__ __forceinline__ void gemm_mainloop3(
    const short* __restrict__ A, const short* __restrict__ B,
    int m0, int n0, short* As, short* Bs, f32x4 acc[4][4], int tid) {
  const int lane = tid & 63;
  const int w = tid >> 6;
  const int wr = (w >> 1) * 64, wc = (w & 1) * 64;
  const int lr = lane & 15;
  const int g = lane >> 4;
  const int rowt = tid >> 2;
  const int csw = ((tid & 3) ^ ((tid >> 3) & 3)) * 8;

  const short* A0 = A + (size_t)(m0 + rowt) * Dm + csw;
  const short* A1 = A + (size_t)(m0 + 64 + rowt) * Dm + csw;
  const short* B0 = B + (size_t)(n0 + rowt) * Dm + csw;
  const short* B1 = B + (size_t)(n0 + 64 + rowt) * Dm + csw;
  short* Ad0 = As + (w * 16) * 32;
  short* Ad1 = As + (64 + w * 16) * 32;
  short* Bd0 = Bs + (w * 16) * 32;
  short* Bd1 = Bs + (64 + w * 16) * 32;

  auto stage = [&](int kt, int buf) {
    const int ko = kt * 32;
    gload16(A0 + ko, Ad0 + buf * 4096);
    gload16(A1 + ko, Ad1 + buf * 4096);
    gload16(B0 + ko, Bd0 + buf * 4096);
    gload16(B1 + ko, Bd1 + buf * 4096);
  };

  const int csel = (g ^ ((lr >> 1) & 3)) * 8;

  stage(0, 0);
  for (int kt = 0; kt < Dm / 32; ++kt) {
    __builtin_amdgcn_s_barrier();
    if (kt + 1 < Dm / 32) {
      stage(kt + 1, (kt + 1) & 1);
      __builtin_amdgcn_sched_barrier(0);
      asm volatile("s_waitcnt vmcnt(4)" ::: "memory");
    } else {
      asm volatile("s_waitcnt vmcnt(0)" ::: "memory");
    }
    __builtin_amdgcn_s_barrier();
    __builtin_amdgcn_sched_barrier(0);
    const int cur = kt & 1;
    short8 a[4], b[4];
#pragma unroll
    for (int mi = 0; mi < 4; ++mi)
      a[mi] = *reinterpret_cast<const short8*>(
          &As[cur * 4096 + (wr + mi * 16 + lr) * 32 + csel]);
#pragma unroll
    for (int ni = 0; ni < 4; ++ni)
      b[ni] = *reinterpret_cast<const short8*>(
          &Bs[cur * 4096 + (wc + ni * 16 + lr) * 32 + csel]);
#pragma unroll
    for (int mi = 0; mi < 4; ++mi)
#pragma unroll
      for (int ni = 0; ni < 4; ++ni)
        acc[mi][ni] = MFMA_BF16(a[mi], b[ni], acc[mi][ni], 0, 0, 0);
  }
}

__global__ __launch_bounds__(256) void gemm_out_kernel(
    const short* __restrict__ Ags, const short* __restrict__ Bts,
    float* __restrict__ Cf, const float* __restrict__ bias) {
  __shared__ __align__(16) short As[2 * 128 * 32];
  __shared__ __align__(16) short Bs[2 * 128 * 32];
  const int tid = threadIdx.x;
  const int m0 = blockIdx.x * 128;
  const int n0 = blockIdx.y * 128;

  f32x4 acc[4][4];
#pragma unroll
  for (int mi = 0; mi < 4; ++mi)
#pragma unroll
    for (int ni = 0; ni < 4; ++ni)
#pragma unroll
      for (int r = 0; r < 4; ++r) acc[mi][ni][r] = 0.f;

  gemm_mainloop3(Ags, Bts, m0, n0, As, Bs, acc, tid);

  const int lane = tid & 63;
  const int w = tid >> 6;
  const int wr = (w >> 1) * 64, wc = (w & 1) * 64;
  const int g = lane >> 4, lr = lane & 15;
#pragma unroll
  for (int mi = 0; mi < 4; ++mi)
#pragma unroll
    for (int ni = 0; ni < 4; ++ni)
#pragma unroll
      for (int r = 0; r < 4; ++r) {
        int mg = m0 + wr + mi * 16 + g * 4 + r;
        int ng = n0 + wc + ni * 16 + lr;
        Cf[(size_t)mg * Dm + ng] = acc[mi][ni][r] + bias[ng];
      }
}

// Flash attention (r13, unchanged): causal, fixed-offset softmax, l via
// ones-MFMA, 3-buffer 2-deep prefetch with counted vmcnt, XCD-local grid,
// T5 setprio on MFMA clusters.
__global__ __launch_bounds__(256) void attn_kernel(
    const short* __restrict__ Qg, const short* __restrict__ Kg,
    const short* __restrict__ Vg, short* __restrict__ Og) {
  __shared__ __align__(16) short Kl[3][64 * 64];
  __shared__ __align__(16) short Vl[3][64 * 64];
  __shared__ __align__(16) short Pl[4][32 * 72];
  const int tid = threadIdx.x;
  const int lane = tid & 63;
  const int w = tid >> 6;
  const int g = lane >> 4;
  const int lr = lane & 15;
  const int bh = blockIdx.x;
  const int pi = blockIdx.y;
  const short* Ks = Kg + ((size_t)bh * NKT << 12);
  const short* Vs = Vg + ((size_t)bh * NKT << 12);
  short* Pw = &Pl[w][0];
  const int b_ = bh >> 4, h_ = bh & 15;

  short8 ones;
#pragma unroll
  for (int j = 0; j < 8; ++j) ones[j] = (short)0x3F80;  // bf16 1.0

  auto stage = [&](int t, int buf) {
#pragma unroll
    for (int i = 0; i < 2; ++i) {
      int ch = w * 2 + i;
      gload16(Ks + ((size_t)t << 12) + ch * 512 + lane * 8, &Kl[buf][ch * 512]);
      gload16(Vs + ((size_t)t << 12) + ch * 512 + lane * 8, &Vl[buf][ch * 512]);
    }
  };

  for (int pass = 0; pass < 2; ++pass) {
    const int qb = pass == 0 ? (15 - pi) : pi;
    const int q0 = qb * 128;
    const int qw = q0 + w * 32;
    const short* Qs = Qg + ((size_t)bh * Tm + q0) * HDm;

    short8 qf[2][2];
#pragma unroll
    for (int mi = 0; mi < 2; ++mi)
#pragma unroll
      for (int kk = 0; kk < 2; ++kk)
        qf[mi][kk] = *reinterpret_cast<const short8*>(
            Qs + (w * 32 + mi * 16 + lr) * HDm + kk * 32 + g * 8);

    f32x4 o[2][4], lacc[2];
#pragma unroll
    for (int mi = 0; mi < 2; ++mi)
#pragma unroll
      for (int r = 0; r < 4; ++r) {
        lacc[mi][r] = 0.f;
#pragma unroll
        for (int di = 0; di < 4; ++di) o[mi][di][r] = 0.f;
      }

    const int nt = q0 / 64 + 2;
    stage(0, 0);
    stage(1, 1);
    for (int t = 0; t < nt; ++t) {
      if (t < nt - 1) asm volatile("s_waitcnt vmcnt(4)" ::: "memory");
      else            asm volatile("s_waitcnt vmcnt(0)" ::: "memory");
      __builtin_amdgcn_s_barrier();
      __builtin_amdgcn_sched_barrier(0);
      if (t + 2 < nt) stage(t + 2, (t + 2) % 3);
      const int cur = t % 3;
      const int k0 = t * 64;
      const bool active = (k0 <= qw + 31);
      if (active) {
        short8 kf[2][4];
#pragma unroll
        for (int ni = 0; ni < 4; ++ni) {
          int row = ni * 16 + lr;
#pragma unroll
          for (int kk = 0; kk < 2; ++kk)
            kf[kk][ni] = *reinterpret_cast<const short8*>(
                &Kl[cur][row * 64 + ((kk * 32 + g * 8) ^ ((row & 7) << 3))]);
        }
        f32x4 s[2][4];
        __builtin_amdgcn_s_setprio(1);
#pragma unroll
        for (int mi = 0; mi < 2; ++mi)
#pragma unroll
          for (int ni = 0; ni < 4; ++ni) {
            f32x4 acc;
#pragma unroll
            for (int r = 0; r < 4; ++r) acc[r] = 0.f;
            acc = MFMA_BF16(qf[mi][0], kf[0][ni], acc, 0, 0, 0);
            acc = MFMA_BF16(qf[mi][1], kf[1][ni], acc, 0, 0, 0);
            s[mi][ni] = acc;
          }
        __builtin_amdgcn_s_setprio(0);
        if (k0 + 63 > qw) {
#pragma unroll
          for (int mi = 0; mi < 2; ++mi)
#pragma unroll
            for (int ni = 0; ni < 4; ++ni)
#pragma unroll
              for (int r = 0; r < 4; ++r)
                if (k0 + ni * 16 + lr > qw + mi * 16 + g * 4 + r) s[mi][ni][r] = -1e30f;
        }
#pragma unroll
        for (int mi = 0; mi < 2; ++mi)
#pragma unroll
          for (int ni = 0; ni < 4; ++ni)
#pragma unroll
            for (int r = 0; r < 4; ++r)
              Pw[(mi * 16 + g * 4 + r) * 72 + ((ni * 16 + lr) ^ (g << 4))] =
                  (short)f2bf(fexp2(s[mi][ni][r]));

        __builtin_amdgcn_s_setprio(1);
#pragma unroll
        for (int kk = 0; kk < 2; ++kk) {
          short8 pf[2];
#pragma unroll
          for (int mi = 0; mi < 2; ++mi)
            pf[mi] = *reinterpret_cast<const short8*>(
                &Pw[(mi * 16 + lr) * 72 + ((kk * 32 + g * 8) ^ ((lr >> 2) << 4))]);
#pragma unroll
          for (int mi = 0; mi < 2; ++mi)
            lacc[mi] = MFMA_BF16(pf[mi], ones, lacc[mi], 0, 0, 0);
#pragma unroll
          for (int di = 0; di < 4; ++di) {
            int d = di * 16 + lr;
            short8 vf = *reinterpret_cast<const short8*>(
                &Vl[cur][d * 64 + ((kk * 32 + g * 8) ^ ((d & 7) << 3))]);
#pragma unroll
            for (int mi = 0; mi < 2; ++mi)
              o[mi][di] = MFMA_BF16(pf[mi], vf, o[mi][di], 0, 0, 0);
          }
        }
        __builtin_amdgcn_s_setprio(0);
      }
    }
    __syncthreads();

#pragma unroll
    for (int mi = 0; mi < 2; ++mi)
#pragma unroll
      for (int di = 0; di < 4; ++di)
#pragma unroll
        for (int r = 0; r < 4; ++r) {
          float ov = o[mi][di][r] / lacc[mi][r];
          int qg = q0 + w * 32 + mi * 16 + g * 4 + r;
          int d_ = di * 16 + lr;
          Og[((size_t)b_ * Tm + qg) * Dm + h_ * HDm + d_] = (short)f2bf(ov);
        }
  }
}

extern "C" void kernel_launch(void* const* d_in, const int* in_sizes, int n_in,
                              void* d_out, int out_size, void* d_ws, size_t ws_size,
                              hipStream_t stream) {
  const float* X = (const float*)d_in[0];
  const float* Wq = (const float*)d_in[1];
  const float* Wk = (const float*)d_in[2];
  const float* Wv = (const float*)d_in[3];
  const float* Wo = (const float*)d_in[4];
  const float* bo = (const float*)d_in[5];
  float* out = (float*)d_out;

  char* ws = (char*)d_ws;
  short* Xb = (short*)ws;  ws += (size_t)Mtot * Dm * 2;
  short* Wqt = (short*)ws; ws += (size_t)Dm * Dm * 2;  // [3072][1024] contiguous
  short* Wkt = (short*)ws; ws += (size_t)Dm * Dm * 2;
  short* Wvt = (short*)ws; ws += (size_t)Dm * Dm * 2;
  short* Wot = (short*)ws; ws += (size_t)Dm * Dm * 2;
  short* Qb = (short*)ws;  ws += (size_t)Mtot * Dm * 2;
  short* Kb = (short*)ws;  ws += (size_t)Mtot * Dm * 2;
  short* Vb = (short*)ws;  ws += (size_t)Mtot * Dm * 2;
  short* Ab = (short*)ws;  ws += (size_t)Mtot * Dm * 2;

  cvt_all_kernel<<<dim3(16, 16, 5), 256, 0, stream>>>(
      X, Wq, Wk, Wv, Wo, Xb, Wqt, Wkt, Wvt, Wot);

  gemm_qkv_kernel<<<dim3(Mtot / 128, 3 * Dm / 128), 256, 0, stream>>>(
      Xb, Wqt, Qb, Kb, Vb);

  attn_kernel<<<dim3(Bb * NHm, 8), 256, 0, stream>>>(Qb, Kb, Vb, Ab);

  gemm_out_kernel<<<dim3(Mtot / 128, Dm / 128), 256, 0, stream>>>(Ab, Wot, out, bo);
}